// Round 10
// baseline (85.619 us; speedup 1.0000x reference)
//
#include <hip/hip_runtime.h>
#include <hip/hip_bf16.h>
#include <math.h>

#define FDIM  128
#define BATCH 4096
#define CNUM  10000

typedef __attribute__((ext_vector_type(8))) short short8;   // 8 bf16 = 4 VGPRs (MFMA A/B frag)
typedef __attribute__((ext_vector_type(4))) float f32x4;    // MFMA C/D frag / float4 store

// ---------------- ws layout (bytes) ----------------
#define WS_FEATB 0            // 4096*128 bf16  = 1048576
#define WS_WB    1048576      // 10000*128 bf16 = 2560000
#define WS_F2    3608576      // 4096 f32
#define WS_W2    3624960      // 10000 f32
#define WS_COR   3664960      // 4096 f32

// exp(-m/1.8) = 2^(-m * C2);  C2 = 1/(1.8*ln2)
#define C2 0.80178372573096f

// async global->LDS, 16B per lane, literal size
#define GL2LDS(g, l) __builtin_amdgcn_global_load_lds(                      \
    (const __attribute__((address_space(1))) void*)(g),                     \
    (__attribute__((address_space(3))) void*)(l), 16, 0, 0)

// Kernel 1: fused prep (f32->bf16 convert + row norms) and cor gather.
__global__ void prep_cor_kernel(const float* __restrict__ feat,
                                const float* __restrict__ weights,
                                const int* __restrict__ label,
                                __hip_bfloat16* __restrict__ featb,
                                __hip_bfloat16* __restrict__ wb,
                                float* __restrict__ f2,
                                float* __restrict__ w2,
                                float* __restrict__ cor) {
    int gw   = (blockIdx.x * blockDim.x + threadIdx.x) >> 6;
    int lane = threadIdx.x & 63;
    if (gw < BATCH + CNUM) {
        const float* src;
        __hip_bfloat16* dst;
        float* nrm;
        if (gw < BATCH) { src = feat    + (size_t)gw * FDIM; dst = featb + (size_t)gw * FDIM; nrm = f2 + gw; }
        else            { int r = gw - BATCH;
                          src = weights + (size_t)r  * FDIM; dst = wb    + (size_t)r  * FDIM; nrm = w2 + r; }
        float2 v = ((const float2*)src)[lane];
        __hip_bfloat162 b2;
        b2.x = __float2bfloat16(v.x);
        b2.y = __float2bfloat16(v.y);
        ((__hip_bfloat162*)dst)[lane] = b2;
        float ss = v.x * v.x + v.y * v.y;
        #pragma unroll
        for (int off = 32; off; off >>= 1) ss += __shfl_down(ss, off, 64);
        if (lane == 0) *nrm = ss;
    } else {
        int s = gw - (BATCH + CNUM);
        if (s >= BATCH) return;
        int lab = label[s];
        float2 f = ((const float2*)(feat    + (size_t)s   * FDIM))[lane];
        float2 w = ((const float2*)(weights + (size_t)lab * FDIM))[lane];
        float dx = f.x - w.x, dy = f.y - w.y;
        float ss = dx * dx + dy * dy;
        #pragma unroll
        for (int off = 32; off; off >>= 1) ss += __shfl_down(ss, off, 64);
        if (lane == 0) cor[s] = __expf(-ss * (1.0f / 1.8f));
    }
}

// Kernel 2: producer/consumer GEMM with LDS output ring.
// 1024 blocks x 512 thr, 1 block/CU (132KB LDS). Block = band (32 rows,
// bx&127) x class-group cg (bx>>7): 10 consecutive tiles t = cg*10+it.
// Waves 0-3 COMPUTE: wave w owns classes [w*32,+32) x 32 rows
// (acc[2][2]); A-tile in LDS dbuf (GL2LDS + chunk-XOR swizzle), B-frags
// from global (L2). Epilogue exp2 -> ds_write into ring (no global
// stores -> compute vmcnt stays clean for counted prefetch waits).
// Waves 4-7 COPY: ring group gi (2 tiles = 1024B/row, written iters
// 2gi..2gi+1) is copied at iters 2gi+2..2gi+3 (last group post-loop):
// each inst = ds_read_b128 ring + global_store_dwordx4 covering 4 rows x
// 256B contiguous segments; back-to-back j-insts extend each row's run
// to 1024B -> DRAM sees ~1KB runs (vs 512B scatter before). Copy-wave
// vmcnt tracks only its own stores (per-wave) -> stores free-run.
// Ring row-stride 1040B (65 x 16B, 65%8==1) -> perfect 8-quad LDS spread
// for both b128 writes and reads.
__launch_bounds__(512, 2)
__global__ void gemm_kernel(const __hip_bfloat16* __restrict__ featb,
                            const __hip_bfloat16* __restrict__ wb,
                            const float* __restrict__ f2,
                            const float* __restrict__ w2,
                            const float* __restrict__ cor,
                            float* __restrict__ out) {
    __shared__ __align__(16) char ldsA[65536];   // A dbuf: 2 x (128 x 256B)
    __shared__ __align__(16) char ring[66560];   // 2 x 32 rows x 1040B
    __shared__ float red[8];

    int bx   = blockIdx.x;
    int band = bx & 127;           // 128 bands x 32 rows
    int cg   = bx >> 7;            // 8 class-groups x 10 tiles
    int tid  = threadIdx.x;
    int wid  = tid >> 6;
    int lane = tid & 63;
    int r16  = lane & 15;
    int kh   = lane >> 4;
    bool cwave = (wid < 4);
    int t0 = cg * 10;

    const char* Ab = (const char*)wb;
    const char* Bb = (const char*)featb;
    char* outb = (char*)out;

    // ---- prologue: scale partial reduction (all) + pf tile0 (compute) ----
    {
        float s = 0.0f;
        #pragma unroll
        for (int i = 0; i < BATCH / 512; ++i) s += cor[tid + i * 512];
        #pragma unroll
        for (int off = 32; off; off >>= 1) s += __shfl_down(s, off, 64);
        if (lane == 0) red[wid] = s;
    }
    if (cwave) {
        #pragma unroll
        for (int p = 0; p < 8; ++p) {
            int idx = tid + p * 256;              // 0..2047
            int row = idx >> 4, chk = idx & 15;
            int gc = t0 * 128 + row; gc = gc < CNUM ? gc : CNUM - 1;
            GL2LDS(Ab + (size_t)gc * 256 + (chk ^ (row & 7)) * 16, ldsA + idx * 16);
        }
    }
    __syncthreads();   // red visible; pf drained (conservative waitcnt)

    float tot = 0.0f;
    #pragma unroll
    for (int i = 0; i < 8; ++i) tot += red[i];
    float avg = fmaxf(tot * (1.0f / BATCH), 0.5f);
    float ls2 = log2f(logf((float)(CNUM - 1)) / avg);

    // compute-wave persistent state
    short8 bfrag[4][2];
    float  f2n[2];
    if (cwave) {
        #pragma unroll
        for (int n = 0; n < 2; ++n) {
            int rowg = band * 32 + n * 16 + r16;
            f2n[n] = f2[rowg];
            #pragma unroll
            for (int kk = 0; kk < 4; ++kk)
                bfrag[kk][n] = *(const short8*)(Bb + (size_t)rowg * 256 + kk * 64 + kh * 16);
        }
    }
    int cw = wid & 3;              // compute: class strip; copy: row octet

    #pragma unroll
    for (int it = 0; it < 10; ++it) {
        if (cwave) {
            int t   = t0 + it;
            int cur = it & 1;
            // prefetch next tile
            if (it < 9) {
                #pragma unroll
                for (int p = 0; p < 8; ++p) {
                    int idx = tid + p * 256;
                    int row = idx >> 4, chk = idx & 15;
                    int gc = (t + 1) * 128 + row; gc = gc < CNUM ? gc : CNUM - 1;
                    GL2LDS(Ab + (size_t)gc * 256 + (chk ^ (row & 7)) * 16,
                           ldsA + (cur ^ 1) * 32768 + idx * 16);
                }
            }
            // w2 for this wave's 2 m-frags
            f32x4 w4[2];
            #pragma unroll
            for (int m = 0; m < 2; ++m) {
                int cm0 = t * 128 + cw * 32 + m * 16 + kh * 4;
                w4[m] = *(const f32x4*)(w2 + (cm0 <= CNUM - 4 ? cm0 : 0));
            }
            // MFMA
            f32x4 acc[2][2];
            #pragma unroll
            for (int m = 0; m < 2; ++m)
                #pragma unroll
                for (int n = 0; n < 2; ++n) acc[m][n] = (f32x4){0.f, 0.f, 0.f, 0.f};
            #pragma unroll
            for (int kk = 0; kk < 4; ++kk) {
                short8 a[2];
                #pragma unroll
                for (int m = 0; m < 2; ++m) {
                    int rowA = cw * 32 + m * 16 + r16;
                    int c = (kk * 4 + kh) ^ (rowA & 7);
                    a[m] = *(const short8*)(ldsA + cur * 32768 + rowA * 256 + c * 16);
                }
                #pragma unroll
                for (int m = 0; m < 2; ++m)
                    #pragma unroll
                    for (int n = 0; n < 2; ++n)
                        acc[m][n] = __builtin_amdgcn_mfma_f32_16x16x32_bf16(a[m], bfrag[kk][n], acc[m][n], 0, 0, 0);
            }
            // epilogue -> ring (group gi = it>>1, slot = it&1, parity = gi&1)
            int rbase = (( (it >> 1) & 1 ) * 33280) + ((it & 1) * 512);
            #pragma unroll
            for (int m = 0; m < 2; ++m) {
                #pragma unroll
                for (int n = 0; n < 2; ++n) {
                    f32x4 v;
                    #pragma unroll
                    for (int r = 0; r < 4; ++r) {
                        float mt2 = fmaf(-2.0f, acc[m][n][r], f2n[n] + w4[m][r]);
                        mt2 = fmaxf(mt2, 0.0f);
                        v[r] = exp2f(fmaf(mt2, -C2, ls2));
                    }
                    *(f32x4*)(ring + rbase + (n * 16 + r16) * 1040 + cw * 128 + m * 64 + kh * 16) = v;
                }
            }
            asm volatile("s_waitcnt vmcnt(0) lgkmcnt(0)" ::: "memory");
        } else {
            // copy waves: at iters >=2, copy group gic=(it>>1)-1, rows q=it&1
            if (it >= 2) {
                int gic = (it >> 1) - 1;
                int p   = gic & 1;
                int q   = it & 1;
                int rowl = cw * 8 + q * 4 + (lane >> 4);       // block-local row
                size_t gr = (size_t)(band * 32 + rowl) * (CNUM * 4);
                int colbase = cg * 5120 + gic * 1024 + r16 * 16;
                #pragma unroll
                for (int j = 0; j < 4; ++j) {
                    int gbyte = colbase + j * 256;
                    f32x4 v = *(const f32x4*)(ring + p * 33280 + rowl * 1040 + r16 * 16 + j * 256);
                    if (gbyte + 16 <= CNUM * 4)
                        *(f32x4*)(outb + gr + gbyte) = v;
                }
            }
            asm volatile("s_waitcnt lgkmcnt(0)" ::: "memory");
        }
        __builtin_amdgcn_sched_barrier(0);
        __builtin_amdgcn_s_barrier();
    }

    // ---- final flush: group 4 (parity 0), copy waves, no barrier needed ----
    if (!cwave) {
        #pragma unroll
        for (int q = 0; q < 2; ++q) {
            int rowl = cw * 8 + q * 4 + (lane >> 4);
            size_t gr = (size_t)(band * 32 + rowl) * (CNUM * 4);
            int colbase = cg * 5120 + 4 * 1024 + r16 * 16;
            #pragma unroll
            for (int j = 0; j < 4; ++j) {
                int gbyte = colbase + j * 256;
                f32x4 v = *(const f32x4*)(ring + rowl * 1040 + r16 * 16 + j * 256);
                if (gbyte + 16 <= CNUM * 4)
                    *(f32x4*)(outb + gr + gbyte) = v;
            }
        }
    }
}

extern "C" void kernel_launch(void* const* d_in, const int* in_sizes, int n_in,
                              void* d_out, int out_size, void* d_ws, size_t ws_size,
                              hipStream_t stream) {
    (void)in_sizes; (void)n_in; (void)out_size; (void)ws_size;
    const float* feat    = (const float*)d_in[0];
    const float* weights = (const float*)d_in[1];
    const int*   label   = (const int*)d_in[2];
    float* out = (float*)d_out;
    char*  ws  = (char*)d_ws;

    __hip_bfloat16* featb = (__hip_bfloat16*)(ws + WS_FEATB);
    __hip_bfloat16* wb    = (__hip_bfloat16*)(ws + WS_WB);
    float* f2  = (float*)(ws + WS_F2);
    float* w2  = (float*)(ws + WS_W2);
    float* cor = (float*)(ws + WS_COR);

    const int total_waves = BATCH + CNUM + BATCH;
    prep_cor_kernel<<<(total_waves + 3) / 4, 256, 0, stream>>>(
        feat, weights, label, featb, wb, f2, w2, cor);

    gemm_kernel<<<1024, 512, 0, stream>>>(featb, wb, f2, w2, cor, out);
}

// Round 11
// 67.994 us; speedup vs baseline: 1.2592x; 1.2592x over previous
//
#include <hip/hip_runtime.h>
#include <hip/hip_bf16.h>
#include <math.h>

#define FDIM  128
#define BATCH 4096
#define CNUM  10000

typedef __attribute__((ext_vector_type(8))) short short8;   // 8 bf16 = 4 VGPRs (MFMA A/B frag)
typedef __attribute__((ext_vector_type(4))) float f32x4;    // MFMA C/D frag / float4 store

// ---------------- ws layout (bytes) ----------------
#define WS_FEATB 0            // 4096*128 bf16  = 1048576
#define WS_WB    1048576      // 10000*128 bf16 = 2560000
#define WS_F2    3608576      // 4096 f32
#define WS_W2    3624960      // 10000 f32
#define WS_COR   3664960      // 4096 f32

// exp(-m/1.8) = 2^(-m * C2);  C2 = 1/(1.8*ln2)
#define C2 0.80178372573096f

#define CGCLS 1280     // classes per class-group (block)
#define GCLS  256      // classes per group (ring flush granularity = 1024B/row)

// Kernel 1: fused prep (f32->bf16 convert + row norms) and cor gather.
__global__ void prep_cor_kernel(const float* __restrict__ feat,
                                const float* __restrict__ weights,
                                const int* __restrict__ label,
                                __hip_bfloat16* __restrict__ featb,
                                __hip_bfloat16* __restrict__ wb,
                                float* __restrict__ f2,
                                float* __restrict__ w2,
                                float* __restrict__ cor) {
    int gw   = (blockIdx.x * blockDim.x + threadIdx.x) >> 6;
    int lane = threadIdx.x & 63;
    if (gw < BATCH + CNUM) {
        const float* src;
        __hip_bfloat16* dst;
        float* nrm;
        if (gw < BATCH) { src = feat    + (size_t)gw * FDIM; dst = featb + (size_t)gw * FDIM; nrm = f2 + gw; }
        else            { int r = gw - BATCH;
                          src = weights + (size_t)r  * FDIM; dst = wb    + (size_t)r  * FDIM; nrm = w2 + r; }
        float2 v = ((const float2*)src)[lane];
        __hip_bfloat162 b2;
        b2.x = __float2bfloat16(v.x);
        b2.y = __float2bfloat16(v.y);
        ((__hip_bfloat162*)dst)[lane] = b2;
        float ss = v.x * v.x + v.y * v.y;
        #pragma unroll
        for (int off = 32; off; off >>= 1) ss += __shfl_down(ss, off, 64);
        if (lane == 0) *nrm = ss;
    } else {
        int s = gw - (BATCH + CNUM);
        if (s >= BATCH) return;
        int lab = label[s];
        float2 f = ((const float2*)(feat    + (size_t)s   * FDIM))[lane];
        float2 w = ((const float2*)(weights + (size_t)lab * FDIM))[lane];
        float dx = f.x - w.x, dy = f.y - w.y;
        float ss = dx * dx + dy * dy;
        #pragma unroll
        for (int off = 32; off; off >>= 1) ss += __shfl_down(ss, off, 64);
        if (lane == 0) cor[s] = __expf(-ss * (1.0f / 1.8f));
    }
}

// Kernel 2: contiguous-run ring GEMM, non-specialized waves, counted vmcnt.
// 1024 blocks (128 bands x 8 class-groups) x 512 thr; 38KB LDS -> 2 blk/CU.
// Block = 32 batch rows x 1280 classes, swept as 5 groups of 256 classes.
// Per group, per wave (wave = 32 cls strip x all 32 rows, acc[2][2]):
//   C: [vmcnt(4): afr loaded (older), keep 4 stores (newer) in flight]
//      16 MFMA from reg-held afr + bfrag -> epilogue (w2 from LDS, exp2)
//      -> ds_write ring (32 rows x 1040B) -> issue next group's 8 afr
//      loads (BEFORE stores, so waiting on them never drains stores)
//   barrier -> S: 4 stores, each ONE 1024B-contiguous row run
//      (lane l -> byte l*16): DRAM sees >=1KB sequential runs per row,
//      extended group-to-group -> no write amplification (R10: 160MB exact)
//   barrier (ring reuse safe: reads done before own store issue).
// A/B fragments from global (wb 2.5MB / featb 1MB, L2-resident; no GL2LDS).
// Store count uniform 4/wave/group (predicate lane-masked, never all-false)
// -> vmcnt(4) is exact. In-order vmcnt retirement per m135.
__launch_bounds__(512, 4)
__global__ void gemm_kernel(const __hip_bfloat16* __restrict__ featb,
                            const __hip_bfloat16* __restrict__ wb,
                            const float* __restrict__ f2,
                            const float* __restrict__ w2,
                            const float* __restrict__ cor,
                            float* __restrict__ out) {
    __shared__ __align__(16) char ring[33280];    // 32 rows x 1040B (16B pad)
    __shared__ float w2l[CGCLS];
    __shared__ float red[8];

    int bx   = blockIdx.x;
    int band = bx & 127;           // 128 bands x 32 rows
    int cg   = bx >> 7;            // 8 class-groups x 1280 classes
    int tid  = threadIdx.x;
    int wid  = tid >> 6;
    int lane = tid & 63;
    int r16  = lane & 15;
    int kh   = lane >> 4;

    const char* Ab = (const char*)wb;
    const char* Bb = (const char*)featb;
    char* outb = (char*)out;

    // ---- prologue (all vm loads drained by the single __syncthreads) ----
    {   // deterministic cor reduction (identical in every block)
        float s = 0.0f;
        #pragma unroll
        for (int i = 0; i < BATCH / 512; ++i) s += cor[tid + i * 512];
        #pragma unroll
        for (int off = 32; off; off >>= 1) s += __shfl_down(s, off, 64);
        if (lane == 0) red[wid] = s;
    }
    #pragma unroll
    for (int p = 0; p < 3; ++p) {   // stage this block's w2 slice into LDS
        int idx = tid + p * 512;
        if (idx < CGCLS) {
            int cls = cg * CGCLS + idx;
            if (cls >= CNUM) cls = CNUM - 1;
            w2l[idx] = w2[cls];
        }
    }
    float f2n[2];
    short8 bfrag[4][2];
    #pragma unroll
    for (int n = 0; n < 2; ++n) {
        int rowg = band * 32 + n * 16 + r16;
        f2n[n] = f2[rowg];
        #pragma unroll
        for (int kk = 0; kk < 4; ++kk)
            bfrag[kk][n] = *(const short8*)(Bb + (size_t)rowg * 256 + kk * 64 + kh * 16);
    }
    short8 afr[4][2];              // A fragments for the CURRENT group
    #pragma unroll
    for (int kk = 0; kk < 4; ++kk)
        #pragma unroll
        for (int m = 0; m < 2; ++m) {
            int cls = cg * CGCLS + wid * 32 + m * 16 + r16;
            if (cls >= CNUM) cls = CNUM - 1;
            afr[kk][m] = *(const short8*)(Ab + (size_t)cls * 256 + kk * 64 + kh * 16);
        }
    __syncthreads();

    float tot = 0.0f;
    #pragma unroll
    for (int i = 0; i < 8; ++i) tot += red[i];
    float avg = fmaxf(tot * (1.0f / BATCH), 0.5f);
    float ls2 = log2f(logf((float)(CNUM - 1)) / avg);

    #pragma unroll
    for (int g = 0; g < 5; ++g) {
        if (g > 0) {
            // afr loads (older) retired; the 4 stores of g-1 (newer) stay in flight
            asm volatile("s_waitcnt vmcnt(4)" ::: "memory");
            __builtin_amdgcn_sched_barrier(0);
        }

        // ---- MFMA from registers ----
        f32x4 acc[2][2];
        #pragma unroll
        for (int m = 0; m < 2; ++m)
            #pragma unroll
            for (int n = 0; n < 2; ++n) acc[m][n] = (f32x4){0.f, 0.f, 0.f, 0.f};
        #pragma unroll
        for (int kk = 0; kk < 4; ++kk)
            #pragma unroll
            for (int m = 0; m < 2; ++m)
                #pragma unroll
                for (int n = 0; n < 2; ++n)
                    acc[m][n] = __builtin_amdgcn_mfma_f32_16x16x32_bf16(afr[kk][m], bfrag[kk][n], acc[m][n], 0, 0, 0);
        __builtin_amdgcn_sched_barrier(0);

        // ---- issue next group's afr loads NOW (before any store) ----
        if (g < 4) {
            #pragma unroll
            for (int kk = 0; kk < 4; ++kk)
                #pragma unroll
                for (int m = 0; m < 2; ++m) {
                    int cls = cg * CGCLS + (g + 1) * GCLS + wid * 32 + m * 16 + r16;
                    if (cls >= CNUM) cls = CNUM - 1;
                    afr[kk][m] = *(const short8*)(Ab + (size_t)cls * 256 + kk * 64 + kh * 16);
                }
        }
        __builtin_amdgcn_sched_barrier(0);

        // ---- epilogue -> ring (lgkm only: w2 from LDS, ds_write ring) ----
        #pragma unroll
        for (int m = 0; m < 2; ++m) {
            int lcl = g * GCLS + wid * 32 + m * 16 + kh * 4;   // local cls idx
            f32x4 w4 = *(const f32x4*)(&w2l[lcl]);
            #pragma unroll
            for (int n = 0; n < 2; ++n) {
                f32x4 v;
                #pragma unroll
                for (int r = 0; r < 4; ++r) {
                    float mt2 = fmaf(-2.0f, acc[m][n][r], f2n[n] + w4[r]);
                    mt2 = fmaxf(mt2, 0.0f);
                    v[r] = exp2f(fmaf(mt2, -C2, ls2));
                }
                int row = n * 16 + r16;
                *(f32x4*)(ring + row * 1040 + wid * 128 + m * 64 + kh * 16) = v;
            }
        }
        asm volatile("s_waitcnt lgkmcnt(0)" ::: "memory");
        __builtin_amdgcn_sched_barrier(0);
        __builtin_amdgcn_s_barrier();          // ring fully written

        // ---- copy phase: 4 stores/wave, each a 1024B-contiguous row run ----
        #pragma unroll
        for (int jr = 0; jr < 4; ++jr) {
            int row = wid * 4 + jr;
            f32x4 rv = *(const f32x4*)(ring + row * 1040 + lane * 16);
            int colbyte = cg * (CGCLS * 4) + g * 1024 + lane * 16;
            if (colbyte + 16 <= CNUM * 4)
                *(f32x4*)(outb + (size_t)(band * 32 + row) * (CNUM * 4) + colbyte) = rv;
        }
        __builtin_amdgcn_sched_barrier(0);
        __builtin_amdgcn_s_barrier();          // reads done -> ring reusable
    }
}

extern "C" void kernel_launch(void* const* d_in, const int* in_sizes, int n_in,
                              void* d_out, int out_size, void* d_ws, size_t ws_size,
                              hipStream_t stream) {
    (void)in_sizes; (void)n_in; (void)out_size; (void)ws_size;
    const float* feat    = (const float*)d_in[0];
    const float* weights = (const float*)d_in[1];
    const int*   label   = (const int*)d_in[2];
    float* out = (float*)d_out;
    char*  ws  = (char*)d_ws;

    __hip_bfloat16* featb = (__hip_bfloat16*)(ws + WS_FEATB);
    __hip_bfloat16* wb    = (__hip_bfloat16*)(ws + WS_WB);
    float* f2  = (float*)(ws + WS_F2);
    float* w2  = (float*)(ws + WS_W2);
    float* cor = (float*)(ws + WS_COR);

    const int total_waves = BATCH + CNUM + BATCH;
    prep_cor_kernel<<<(total_waves + 3) / 4, 256, 0, stream>>>(
        feat, weights, label, featb, wb, f2, w2, cor);

    gemm_kernel<<<1024, 512, 0, stream>>>(featb, wb, f2, w2, cor, out);
}

// Round 12
// 47.487 us; speedup vs baseline: 1.8030x; 1.4319x over previous
//
#include <hip/hip_runtime.h>
#include <hip/hip_bf16.h>
#include <math.h>

#define FDIM  128
#define BATCH 4096
#define CNUM  10000

typedef __attribute__((ext_vector_type(8))) short short8;   // 8 bf16 = 4 VGPRs (MFMA A/B frag)
typedef __attribute__((ext_vector_type(4))) float f32x4;    // MFMA C/D frag / float4 store

// ---------------- ws layout (bytes) ----------------
#define WS_FEATB 0            // 4096*128 bf16  = 1048576
#define WS_WB    1048576      // 10000*128 bf16 = 2560000
#define WS_F2    3608576      // 4096 f32
#define WS_W2    3624960      // 10000 f32
#define WS_COR   3664960      // 4096 f32

// exp(-m/1.8) = 2^(-m * C2);  C2 = 1/(1.8*ln2)
#define C2 0.80178372573096f

#define CGCLS 640      // classes per class-group (16 groups x 640 = 10240 >= CNUM)

// async global->LDS, 16B per lane, literal size
#define GL2LDS(g, l) __builtin_amdgcn_global_load_lds(                      \
    (const __attribute__((address_space(1))) void*)(g),                     \
    (__attribute__((address_space(3))) void*)(l), 16, 0, 0)

// Kernel 1: fused prep (f32->bf16 convert + row norms) and cor gather.
__global__ void prep_cor_kernel(const float* __restrict__ feat,
                                const float* __restrict__ weights,
                                const int* __restrict__ label,
                                __hip_bfloat16* __restrict__ featb,
                                __hip_bfloat16* __restrict__ wb,
                                float* __restrict__ f2,
                                float* __restrict__ w2,
                                float* __restrict__ cor) {
    int gw   = (blockIdx.x * blockDim.x + threadIdx.x) >> 6;
    int lane = threadIdx.x & 63;
    if (gw < BATCH + CNUM) {
        const float* src;
        __hip_bfloat16* dst;
        float* nrm;
        if (gw < BATCH) { src = feat    + (size_t)gw * FDIM; dst = featb + (size_t)gw * FDIM; nrm = f2 + gw; }
        else            { int r = gw - BATCH;
                          src = weights + (size_t)r  * FDIM; dst = wb    + (size_t)r  * FDIM; nrm = w2 + r; }
        float2 v = ((const float2*)src)[lane];
        __hip_bfloat162 b2;
        b2.x = __float2bfloat16(v.x);
        b2.y = __float2bfloat16(v.y);
        ((__hip_bfloat162*)dst)[lane] = b2;
        float ss = v.x * v.x + v.y * v.y;
        #pragma unroll
        for (int off = 32; off; off >>= 1) ss += __shfl_down(ss, off, 64);
        if (lane == 0) *nrm = ss;
    } else {
        int s = gw - (BATCH + CNUM);
        if (s >= BATCH) return;
        int lab = label[s];
        float2 f = ((const float2*)(feat    + (size_t)s   * FDIM))[lane];
        float2 w = ((const float2*)(weights + (size_t)lab * FDIM))[lane];
        float dx = f.x - w.x, dy = f.y - w.y;
        float ss = dx * dx + dy * dy;
        #pragma unroll
        for (int off = 32; off; off >>= 1) ss += __shfl_down(ss, off, 64);
        if (lane == 0) cor[s] = __expf(-ss * (1.0f / 1.8f));
    }
}

// Kernel 2: R8 skeleton + intra-phase store spreading.
// 512 blocks x 512 thr, 2 blk/CU. Block = band (128 rows, bx&31) x
// class-group cg (bx>>5): 5 CONTIGUOUS tiles, cls base = cg*640 + it*128.
// A-LDS double buffer via GL2LDS + chunk-XOR swizzle; bfrag (featb) in
// VGPR; w2 slice staged to LDS in prologue; scale reduced in prologue.
// Inner loop split into TWO m-pair sub-phases: {8 MFMA (2 indep acc
// chains) -> epilogue -> 4 stores} x2 -> stores issue mid-phase AND
// end-phase (burst density 2x vs R8), MFMA of one pair overlaps store
// issue of the other.
// vm ops/phase: 4 GL2LDS then 8 stores -> s_waitcnt vmcnt(8) at phase end
// retires exactly the prefetch, keeps all 8 stores in flight across the
// barrier. Tail safety: only tiles whose PREDECESSOR issues 8 unmasked
// stores are consumed (cg=15: it<=3 predecessors all <10000... it=2 tile
// classes 9856..9984 unmasked ✓; it=4's garbage-staged case has all
// stores masked).
__launch_bounds__(512, 4)
__global__ void gemm_kernel(const __hip_bfloat16* __restrict__ featb,
                            const __hip_bfloat16* __restrict__ wb,
                            const float* __restrict__ f2,
                            const float* __restrict__ w2,
                            const float* __restrict__ cor,
                            float* __restrict__ out) {
    __shared__ __align__(16) char lds[65536];    // A dbuf: buf0 | buf1
    __shared__ __align__(16) float w2l[CGCLS];
    __shared__ float red[8];

    int bx   = blockIdx.x;
    int band = bx & 31;            // 32 bands x 128 batch rows
    int cg   = bx >> 5;            // 16 class-groups x 640 contiguous classes
    int tid  = threadIdx.x;
    int wid  = tid >> 6;
    int lane = tid & 63;
    int r16  = lane & 15;
    int kh   = lane >> 4;
    int aoff = (wid & 1) * 64;     // class half within 128-tile
    int boff = (wid >> 1) * 32;    // row quarter within 128-band

    const char* Ab = (const char*)wb;
    const char* Bb = (const char*)featb;

    // ---- prologue ----
    #pragma unroll
    for (int p = 0; p < 4; ++p) {          // stage tile 0 into buf0
        int idx = tid + p * 512;
        int row = idx >> 4, chk = idx & 15;
        int gc = cg * CGCLS + row; gc = gc < CNUM ? gc : CNUM - 1;
        GL2LDS(Ab + (size_t)gc * 256 + (chk ^ (row & 7)) * 16, lds + idx * 16);
    }
    {   // deterministic cor reduction (identical in every block)
        float s = 0.0f;
        #pragma unroll
        for (int i = 0; i < BATCH / 512; ++i) s += cor[tid + i * 512];
        #pragma unroll
        for (int off = 32; off; off >>= 1) s += __shfl_down(s, off, 64);
        if (lane == 0) red[wid] = s;
    }
    #pragma unroll
    for (int p = 0; p < 2; ++p) {          // stage w2 slice
        int idx = tid + p * 512;
        if (idx < CGCLS) {
            int cls = cg * CGCLS + idx;
            w2l[idx] = (cls < CNUM) ? w2[cls] : 0.0f;
        }
    }
    float f2n[2];
    short8 bfrag[4][2];
    #pragma unroll
    for (int n = 0; n < 2; ++n) {
        int rowg = band * 128 + boff + n * 16 + r16;
        f2n[n] = f2[rowg];
        #pragma unroll
        for (int kk = 0; kk < 4; ++kk)
            bfrag[kk][n] = *(const short8*)(Bb + (size_t)rowg * 256 + kk * 64 + kh * 16);
    }
    __syncthreads();   // full drain once (staging + red + w2l visible)

    float tot = 0.0f;
    #pragma unroll
    for (int i = 0; i < 8; ++i) tot += red[i];
    float avg = fmaxf(tot * (1.0f / BATCH), 0.5f);
    float ls2 = log2f(logf((float)(CNUM - 1)) / avg);

    #pragma unroll
    for (int it = 0; it < 5; ++it) {
        int cur = it & 1;

        // prefetch next tile into the other buffer (pinned before compute)
        if (it < 4) {
            #pragma unroll
            for (int p = 0; p < 4; ++p) {
                int idx = tid + p * 512;
                int row = idx >> 4, chk = idx & 15;
                int gc = cg * CGCLS + (it + 1) * 128 + row;
                gc = gc < CNUM ? gc : CNUM - 1;
                GL2LDS(Ab + (size_t)gc * 256 + (chk ^ (row & 7)) * 16,
                       lds + (cur ^ 1) * 32768 + idx * 16);
            }
        }
        __builtin_amdgcn_sched_barrier(0);   // prefetch issued before compute

        const char* Abuf = lds + cur * 32768;

        // ---- two m-pair sub-phases: MFMA -> epilogue -> stores each ----
        #pragma unroll
        for (int mp = 0; mp < 2; ++mp) {
            f32x4 acc[2][2];
            #pragma unroll
            for (int mm = 0; mm < 2; ++mm)
                #pragma unroll
                for (int n = 0; n < 2; ++n) acc[mm][n] = (f32x4){0.f, 0.f, 0.f, 0.f};

            #pragma unroll
            for (int kk = 0; kk < 4; ++kk) {
                short8 a0, a1;
                {
                    int row0 = aoff + (mp * 2 + 0) * 16 + r16;
                    int c0 = (kk * 4 + kh) ^ (row0 & 7);
                    a0 = *(const short8*)(Abuf + row0 * 256 + c0 * 16);
                    int row1 = aoff + (mp * 2 + 1) * 16 + r16;
                    int c1 = (kk * 4 + kh) ^ (row1 & 7);
                    a1 = *(const short8*)(Abuf + row1 * 256 + c1 * 16);
                }
                #pragma unroll
                for (int n = 0; n < 2; ++n) {
                    acc[0][n] = __builtin_amdgcn_mfma_f32_16x16x32_bf16(a0, bfrag[kk][n], acc[0][n], 0, 0, 0);
                    acc[1][n] = __builtin_amdgcn_mfma_f32_16x16x32_bf16(a1, bfrag[kk][n], acc[1][n], 0, 0, 0);
                }
            }

            // epilogue + 4 stores for this pair (stores spread mid/end phase)
            #pragma unroll
            for (int mm = 0; mm < 2; ++mm) {
                int lcl = it * 128 + aoff + (mp * 2 + mm) * 16 + kh * 4;
                int cm0 = cg * CGCLS + lcl;
                bool ok = cm0 < CNUM;               // cm0,CNUM % 4 == 0 -> no straddle
                f32x4 w4 = *(const f32x4*)(&w2l[lcl]);
                #pragma unroll
                for (int n = 0; n < 2; ++n) {
                    f32x4 v;
                    #pragma unroll
                    for (int r = 0; r < 4; ++r) {
                        float mt2 = fmaf(-2.0f, acc[mm][n][r], f2n[n] + w4[r]);
                        mt2 = fmaxf(mt2, 0.0f);
                        v[r] = exp2f(fmaf(mt2, -C2, ls2));
                    }
                    if (ok) {
                        size_t rg = (size_t)(band * 128 + boff + n * 16 + r16);
                        *(f32x4*)(out + rg * CNUM + cm0) = v;
                    }
                }
            }
        }

        // counted-vmcnt barrier: retire the 4 prefetch GL2LDS (oldest),
        // keep all 8 stores in flight under the next tile's compute.
        asm volatile("s_waitcnt vmcnt(8)" ::: "memory");
        __builtin_amdgcn_sched_barrier(0);
        __builtin_amdgcn_s_barrier();
    }
}

extern "C" void kernel_launch(void* const* d_in, const int* in_sizes, int n_in,
                              void* d_out, int out_size, void* d_ws, size_t ws_size,
                              hipStream_t stream) {
    (void)in_sizes; (void)n_in; (void)out_size; (void)ws_size;
    const float* feat    = (const float*)d_in[0];
    const float* weights = (const float*)d_in[1];
    const int*   label   = (const int*)d_in[2];
    float* out = (float*)d_out;
    char*  ws  = (char*)d_ws;

    __hip_bfloat16* featb = (__hip_bfloat16*)(ws + WS_FEATB);
    __hip_bfloat16* wb    = (__hip_bfloat16*)(ws + WS_WB);
    float* f2  = (float*)(ws + WS_F2);
    float* w2  = (float*)(ws + WS_W2);
    float* cor = (float*)(ws + WS_COR);

    const int total_waves = BATCH + CNUM + BATCH;
    prep_cor_kernel<<<(total_waves + 3) / 4, 256, 0, stream>>>(
        feat, weights, label, featb, wb, f2, w2, cor);

    gemm_kernel<<<512, 512, 0, stream>>>(featb, wb, f2, w2, cor, out);
}